// Round 4
// baseline (26.972 us; speedup 1.0000x reference)
//
#include <hip/hip_runtime.h>
#include <math.h>

// Tiny MLP: 6 -> 8 (relu) -> 4 (relu) -> 2 (relu) -> 1, then softplus.
// R1: native __expf/__logf transcendentals.
// R2: packed fp32 math — process rows in pairs as <2 x float> so the
//     backend emits v_pk_fma_f32 / v_pk_max_f32 (gfx90a+ packed FP32).
// R3: fix compile — use clang ext_vector float4 (not HIP_vector_type) for
//     __builtin_nontemporal_store.

typedef float v2f __attribute__((ext_vector_type(2)));
typedef float v4f __attribute__((ext_vector_type(4)));

__device__ __forceinline__ v2f vmax0(v2f a) {
#if __has_builtin(__builtin_elementwise_max)
    return __builtin_elementwise_max(a, (v2f)0.0f);
#else
    v2f r; r.x = fmaxf(a.x, 0.0f); r.y = fmaxf(a.y, 0.0f); return r;
#endif
}

__global__ __launch_bounds__(256) void encoder_mlp_kernel(
    const float* __restrict__ x,
    const float* __restrict__ W1, const float* __restrict__ b1,
    const float* __restrict__ W7, const float* __restrict__ b7,
    const float* __restrict__ W8, const float* __restrict__ b8,
    const float* __restrict__ W9, const float* __restrict__ b9,
    float* __restrict__ out, int n_rows)
{
    const int t = blockIdx.x * blockDim.x + threadIdx.x;
    const long long row0 = (long long)t * 4;
    if (row0 >= n_rows) return;

    const bool full_quad = (row0 + 4 <= n_rows);

    v2f xp[2][6];   // [pair][feature] = {row_even, row_odd}

    if (full_quad) {
        const v4f* xin = reinterpret_cast<const v4f*>(x) + (size_t)t * 6;
        v4f v0 = xin[0], v1 = xin[1], v2 = xin[2],
            v3 = xin[3], v4 = xin[4], v5 = xin[5];
        // pair 0 = rows 0,1
        xp[0][0] = (v2f){v0.x, v1.z}; xp[0][1] = (v2f){v0.y, v1.w};
        xp[0][2] = (v2f){v0.z, v2.x}; xp[0][3] = (v2f){v0.w, v2.y};
        xp[0][4] = (v2f){v1.x, v2.z}; xp[0][5] = (v2f){v1.y, v2.w};
        // pair 1 = rows 2,3
        xp[1][0] = (v2f){v3.x, v4.z}; xp[1][1] = (v2f){v3.y, v4.w};
        xp[1][2] = (v2f){v3.z, v5.x}; xp[1][3] = (v2f){v3.w, v5.y};
        xp[1][4] = (v2f){v4.x, v5.z}; xp[1][5] = (v2f){v4.y, v5.w};
    } else {
        #pragma unroll
        for (int p = 0; p < 2; ++p) {
            #pragma unroll
            for (int k = 0; k < 6; ++k) {
                long long ra = row0 + 2 * p, rb = ra + 1;
                float a = (ra < n_rows) ? x[ra * 6 + k] : 0.0f;
                float b = (rb < n_rows) ? x[rb * 6 + k] : 0.0f;
                xp[p][k] = (v2f){a, b};
            }
        }
    }

    float res[4];
    #pragma unroll
    for (int p = 0; p < 2; ++p) {
        // layer 1: 6 -> 8, relu  (packed over the row pair)
        v2f h1[8];
        #pragma unroll
        for (int j = 0; j < 8; ++j) {
            v2f acc = (v2f)b1[j];
            #pragma unroll
            for (int k = 0; k < 6; ++k) acc += W1[j * 6 + k] * xp[p][k];
            h1[j] = vmax0(acc);
        }
        // layer 7: 8 -> 4, relu
        v2f h7[4];
        #pragma unroll
        for (int j = 0; j < 4; ++j) {
            v2f acc = (v2f)b7[j];
            #pragma unroll
            for (int k = 0; k < 8; ++k) acc += W7[j * 8 + k] * h1[k];
            h7[j] = vmax0(acc);
        }
        // layer 8: 4 -> 2, relu
        v2f h8[2];
        #pragma unroll
        for (int j = 0; j < 2; ++j) {
            v2f acc = (v2f)b8[j];
            #pragma unroll
            for (int k = 0; k < 4; ++k) acc += W8[j * 4 + k] * h7[k];
            h8[j] = vmax0(acc);
        }
        // layer 9: 2 -> 1, then softplus (trans pipe is scalar-only)
        v2f z = W9[0] * h8[0] + W9[1] * h8[1] + (v2f)b9[0];
        v2f az; az.x = fabsf(z.x); az.y = fabsf(z.y);
        v2f e;  e.x = __expf(-az.x); e.y = __expf(-az.y);
        v2f l;  l.x = __logf(1.0f + e.x); l.y = __logf(1.0f + e.y);
        v2f r = vmax0(z) + l;
        res[2 * p]     = r.x;
        res[2 * p + 1] = r.y;
    }

    if (full_quad) {
        v4f o;
        o.x = res[0]; o.y = res[1]; o.z = res[2]; o.w = res[3];
        __builtin_nontemporal_store(o, reinterpret_cast<v4f*>(out) + t);
    } else {
        #pragma unroll
        for (int r = 0; r < 4; ++r) {
            long long row = row0 + r;
            if (row < n_rows) out[row] = res[r];
        }
    }
}

extern "C" void kernel_launch(void* const* d_in, const int* in_sizes, int n_in,
                              void* d_out, int out_size, void* d_ws, size_t ws_size,
                              hipStream_t stream) {
    const float* x  = (const float*)d_in[0];
    const float* W1 = (const float*)d_in[1];
    const float* b1 = (const float*)d_in[2];
    const float* W7 = (const float*)d_in[3];
    const float* b7 = (const float*)d_in[4];
    const float* W8 = (const float*)d_in[5];
    const float* b8 = (const float*)d_in[6];
    const float* W9 = (const float*)d_in[7];
    const float* b9 = (const float*)d_in[8];
    float* out = (float*)d_out;

    const int n_rows = in_sizes[0] / 6;               // 4194304
    const int n_threads = (n_rows + 3) / 4;           // 4 rows per thread
    const int block = 256;
    const int grid = (n_threads + block - 1) / block; // 4096 blocks

    encoder_mlp_kernel<<<grid, block, 0, stream>>>(
        x, W1, b1, W7, b7, W8, b8, W9, b9, out, n_rows);
}